// Round 11
// baseline (41.737 us; speedup 1.0000x reference)
//
#include <hip/hip_runtime.h>
#include <hip/hip_bf16.h>
#include <hip/hip_fp16.h>

#define NXg 128
#define NYg 128
#define NZg 16
#define NPT (NXg * NYg * NZg)   // 262144
#define Hh 32
#define Ww 88
#define Cc 80
#define HWc (Hh * Ww)
#define CSPLIT 2
#define CPB (Cc / CSPLIT)       // 40 channels per block
#define NG (Cc / 4)             // 20 groups of 4 channels
#define BLK 256

// feat (B,C,H,W) fp32 -> featH (B, NG, H*W, 4) fp16 : pixel stride 8B in a group
__global__ __launch_bounds__(256) void fvt_tohalf(
    const float* __restrict__ feat, unsigned short* __restrict__ featH, int total)
{
    int t = blockIdx.x * 256 + threadIdx.x;   // t = ((b*NG+g)*HWc + p)
    if (t >= total) return;
    int p = t % HWc; int r = t / HWc;
    int g = r % NG;  int b = r / NG;
    const float* src = feat + ((size_t)(b * Cc + g * 4)) * HWc + p;
    ushort4 px;
    px.x = __half_as_ushort(__float2half(src[0 * HWc]));
    px.y = __half_as_ushort(__float2half(src[1 * HWc]));
    px.z = __half_as_ushort(__float2half(src[2 * HWc]));
    px.w = __half_as_ushort(__float2half(src[3 * HWc]));
    *reinterpret_cast<ushort4*>(featH + (size_t)t * 4) = px;
}

union U2F2 { unsigned u; __half2 h; };
__device__ __forceinline__ float2 cvt2(unsigned u) {
    U2F2 c; c.u = u;
    return __half22float2(c.h);
}

__global__ __launch_bounds__(BLK) void fvt_kernel(
    const unsigned short* __restrict__ featH,  // (B, NG, H*W, 4) fp16
    const float* __restrict__ intrin,
    const float* __restrict__ extrin,
    const float* __restrict__ bda,
    float* __restrict__ out)                   // (B, C, NX, NY, NZ)
{
    const int b  = blockIdx.y;
    const int cq = blockIdx.z;
    const int t  = blockIdx.x * blockDim.x + threadIdx.x;
    const int n0 = t << 2;              // 4 consecutive n (same z-column)
    if (n0 >= NPT) return;

    const float* In = intrin + b * 16;
    const float* Ex = extrin + b * 16;
    const float* Bd = bda    + b * 16;

    float K[3][3];
#pragma unroll
    for (int r = 0; r < 3; ++r)
#pragma unroll
        for (int c = 0; c < 3; ++c)
            K[r][c] = In[r * 4 + c] * (r == 2 ? 1.0f : 0.125f);

    float P[3][4];
#pragma unroll
    for (int r = 0; r < 3; ++r)
#pragma unroll
        for (int c = 0; c < 4; ++c)
            P[r][c] = K[r][0] * Ex[0 * 4 + c] + K[r][1] * Ex[1 * 4 + c] + K[r][2] * Ex[2 * 4 + c];

    float M[3][4];
#pragma unroll
    for (int r = 0; r < 3; ++r)
#pragma unroll
        for (int c = 0; c < 4; ++c)
            M[r][c] = P[r][0] * Bd[0 * 4 + c] + P[r][1] * Bd[1 * 4 + c]
                    + P[r][2] * Bd[2 * 4 + c] + P[r][3] * Bd[3 * 4 + c];

    const int iz0 = n0 & (NZg - 1);
    const int iy  = (n0 >> 4) & (NYg - 1);
    const int ix  = n0 >> 11;
    const float xf = -51.2f + (float)ix * 0.8f;
    const float yf = -51.2f + (float)iy * 0.8f;

    const float px0 = fmaf(M[0][0], xf, fmaf(M[0][1], yf, M[0][3]));
    const float py0 = fmaf(M[1][0], xf, fmaf(M[1][1], yf, M[1][3]));
    const float pz0 = fmaf(M[2][0], xf, fmaf(M[2][1], yf, M[2][3]));

    int   pix[4][2];    // [j][k: y0/y1]  halfword offset of the x-pair load
    float wlo[4][2];
    float whi[4][2];
    bool  vj [4];
    bool  anyv = false;

#pragma unroll
    for (int j = 0; j < 4; ++j) {
        const float zf = -5.0f + (float)(iz0 + j) * 0.5f;

        const float px = fmaf(M[0][2], zf, px0);
        const float py = fmaf(M[1][2], zf, py0);
        const float pz = fmaf(M[2][2], zf, pz0);

        // x = (px/pz)*(W-1)/W ; y = (py/pz)*(H-1)/H  (algebraic fold of the
        // reference's u/v chain). rcp: pz=0 -> inf/NaN -> isfinite fallback.
        const float rz = __builtin_amdgcn_rcpf(pz);
        float x = px * rz * (87.0f / 88.0f);
        float y = py * rz * (31.0f / 32.0f);
        const bool fin = __builtin_isfinite(x) && __builtin_isfinite(y);
        x = fin ? x : -10.0f;
        y = fin ? y : -10.0f;

        const float x0 = floorf(x);
        const float y0 = floorf(y);
        const float x1 = x0 + 1.0f;
        const float y1 = y0 + 1.0f;
        const float wx1 = x - x0, wx0 = 1.0f - wx1;
        const float wy1 = y - y0, wy0 = 1.0f - wy1;

        const bool vx0 = (x0 >= 0.0f) && (x0 < (float)Ww);
        const bool vx1 = (x1 >= 0.0f) && (x1 < (float)Ww);
        const bool vy0 = (y0 >= 0.0f) && (y0 < (float)Hh);
        const bool vy1 = (y1 >= 0.0f) && (y1 < (float)Hh);
        const float w00 = (vx0 && vy0) ? wx0 * wy0 : 0.0f;
        const float w10 = (vx1 && vy0) ? wx1 * wy0 : 0.0f;
        const float w01 = (vx0 && vy1) ? wx0 * wy1 : 0.0f;
        const float w11 = (vx1 && vy1) ? wx1 * wy1 : 0.0f;

        const float xb  = fminf(fmaxf(x0, 0.0f), 86.0f);
        const float y0c = fminf(fmaxf(y0, 0.0f), 31.0f);
        const float y1c = fminf(fmaxf(y1, 0.0f), 31.0f);

        const int xbi = (int)xb;
        pix[j][0] = ((int)y0c * Ww + xbi) * 4;
        pix[j][1] = ((int)y1c * Ww + xbi) * 4;

        const float lo_is_x0 = (x0 == xb) ? 1.0f : 0.0f;
        const float lo_is_x1 = (x1 == xb) ? 1.0f : 0.0f;
        const float hi_is_x0 = (x0 == xb + 1.0f) ? 1.0f : 0.0f;
        const float hi_is_x1 = (x1 == xb + 1.0f) ? 1.0f : 0.0f;
        wlo[j][0] = lo_is_x0 * w00 + lo_is_x1 * w10;
        whi[j][0] = hi_is_x0 * w00 + hi_is_x1 * w10;
        wlo[j][1] = lo_is_x0 * w01 + lo_is_x1 * w11;
        whi[j][1] = hi_is_x0 * w01 + hi_is_x1 * w11;

        vj[j] = (w00 + w10 + w01 + w11) > 0.0f;
        anyv |= vj[j];
    }

    float* ob = out + ((size_t)b * Cc + cq * CPB) * (size_t)NPT + n0;

    if (!anyv) {
        const float4 z4 = make_float4(0.0f, 0.0f, 0.0f, 0.0f);
#pragma unroll
        for (int q = 0; q < CPB; ++q)
            *reinterpret_cast<float4*>(ob + (size_t)q * NPT) = z4;
        return;
    }

    const unsigned short* fb = featH + ((size_t)b * NG + cq * (CPB / 4)) * (size_t)(HWc * 4);

#pragma unroll 2
    for (int cg = 0; cg < CPB / 4; ++cg) {
        const unsigned short* fg = fb + (size_t)cg * (HWc * 4);
        float acc[4][4];   // [cc][j]
#pragma unroll
        for (int cc = 0; cc < 4; ++cc)
#pragma unroll
            for (int j = 0; j < 4; ++j) acc[cc][j] = 0.0f;

#pragma unroll
        for (int j = 0; j < 4; ++j) {
            if (vj[j]) {
#pragma unroll
                for (int k = 0; k < 2; ++k) {
                    const uint4 raw = *reinterpret_cast<const uint4*>(fg + pix[j][k]);
                    const float wl = wlo[j][k];
                    const float wh = whi[j][k];
                    const float2 lo01 = cvt2(raw.x);
                    const float2 lo23 = cvt2(raw.y);
                    const float2 hi01 = cvt2(raw.z);
                    const float2 hi23 = cvt2(raw.w);
                    acc[0][j] = fmaf(wl, lo01.x, fmaf(wh, hi01.x, acc[0][j]));
                    acc[1][j] = fmaf(wl, lo01.y, fmaf(wh, hi01.y, acc[1][j]));
                    acc[2][j] = fmaf(wl, lo23.x, fmaf(wh, hi23.x, acc[2][j]));
                    acc[3][j] = fmaf(wl, lo23.y, fmaf(wh, hi23.y, acc[3][j]));
                }
            }
        }
#pragma unroll
        for (int cc = 0; cc < 4; ++cc) {
            *reinterpret_cast<float4*>(ob + (size_t)(cg * 4 + cc) * NPT) =
                make_float4(acc[cc][0], acc[cc][1], acc[cc][2], acc[cc][3]);
        }
    }
}

extern "C" void kernel_launch(void* const* d_in, const int* in_sizes, int n_in,
                              void* d_out, int out_size, void* d_ws, size_t ws_size,
                              hipStream_t stream) {
    const float* feat   = (const float*)d_in[0];
    const float* intrin = (const float*)d_in[1];
    const float* extrin = (const float*)d_in[2];
    const float* bda    = (const float*)d_in[3];
    float* out = (float*)d_out;
    unsigned short* featH = (unsigned short*)d_ws;

    const int B = in_sizes[0] / (Cc * HWc);
    const int total = B * NG * HWc;

    fvt_tohalf<<<(total + 255) / 256, 256, 0, stream>>>(feat, featH, total);

    dim3 block(BLK);
    dim3 grid(NPT / 4 / BLK, B, CSPLIT);
    fvt_kernel<<<grid, block, 0, stream>>>(featH, intrin, extrin, bda, out);
}

// Round 12
// 40.447 us; speedup vs baseline: 1.0319x; 1.0319x over previous
//
#include <hip/hip_runtime.h>
#include <hip/hip_bf16.h>
#include <hip/hip_fp16.h>

#define NXg 128
#define NYg 128
#define NZg 16
#define NPT (NXg * NYg * NZg)   // 262144
#define Hh 32
#define Ww 88
#define Cc 80
#define HWc (Hh * Ww)
#define CSPLIT 4
#define CPB (Cc / CSPLIT)       // 20 channels per block
#define NCGPB (CPB / 4)         // 5 slices (4-ch groups) per block
#define NG (Cc / 4)             // 20 groups of 4 channels
#define BLK 512

// feat (B,C,H,W) fp32 -> featH (B, NG, H*W, 4) fp16 : pixel stride 8B in a group
__global__ __launch_bounds__(256) void fvt_tohalf(
    const float* __restrict__ feat, unsigned short* __restrict__ featH, int total)
{
    int t = blockIdx.x * 256 + threadIdx.x;   // t = ((b*NG+g)*HWc + p)
    if (t >= total) return;
    int p = t % HWc; int r = t / HWc;
    int g = r % NG;  int b = r / NG;
    const float* src = feat + ((size_t)(b * Cc + g * 4)) * HWc + p;
    ushort4 px;
    px.x = __half_as_ushort(__float2half(src[0 * HWc]));
    px.y = __half_as_ushort(__float2half(src[1 * HWc]));
    px.z = __half_as_ushort(__float2half(src[2 * HWc]));
    px.w = __half_as_ushort(__float2half(src[3 * HWc]));
    *reinterpret_cast<ushort4*>(featH + (size_t)t * 4) = px;
}

union U2F2 { unsigned u; __half2 h; };
__device__ __forceinline__ float2 cvt2(unsigned u) {
    U2F2 c; c.u = u;
    return __half22float2(c.h);
}

__global__ __launch_bounds__(BLK) void fvt_kernel(
    const unsigned short* __restrict__ featH,  // (B, NG, H*W, 4) fp16
    const float* __restrict__ intrin,
    const float* __restrict__ extrin,
    const float* __restrict__ bda,
    float* __restrict__ out)                   // (B, C, NX, NY, NZ)
{
    const int b  = blockIdx.y;
    const int cq = blockIdx.z;
    const int t  = blockIdx.x * blockDim.x + threadIdx.x;
    const int n0 = t << 2;              // 4 consecutive n (same z-column)
    if (n0 >= NPT) return;

    const float* In = intrin + b * 16;
    const float* Ex = extrin + b * 16;
    const float* Bd = bda    + b * 16;

    float K[3][3];
#pragma unroll
    for (int r = 0; r < 3; ++r)
#pragma unroll
        for (int c = 0; c < 3; ++c)
            K[r][c] = In[r * 4 + c] * (r == 2 ? 1.0f : 0.125f);

    float P[3][4];
#pragma unroll
    for (int r = 0; r < 3; ++r)
#pragma unroll
        for (int c = 0; c < 4; ++c)
            P[r][c] = K[r][0] * Ex[0 * 4 + c] + K[r][1] * Ex[1 * 4 + c] + K[r][2] * Ex[2 * 4 + c];

    float M[3][4];
#pragma unroll
    for (int r = 0; r < 3; ++r)
#pragma unroll
        for (int c = 0; c < 4; ++c)
            M[r][c] = P[r][0] * Bd[0 * 4 + c] + P[r][1] * Bd[1 * 4 + c]
                    + P[r][2] * Bd[2 * 4 + c] + P[r][3] * Bd[3 * 4 + c];

    const int iz0 = n0 & (NZg - 1);
    const int iy  = (n0 >> 4) & (NYg - 1);
    const int ix  = n0 >> 11;
    const float xf = -51.2f + (float)ix * 0.8f;
    const float yf = -51.2f + (float)iy * 0.8f;

    const float px0 = fmaf(M[0][0], xf, fmaf(M[0][1], yf, M[0][3]));
    const float py0 = fmaf(M[1][0], xf, fmaf(M[1][1], yf, M[1][3]));
    const float pz0 = fmaf(M[2][0], xf, fmaf(M[2][1], yf, M[2][3]));

    int   pix[4][2];    // [j][k: y0/y1]  halfword offset of the x-pair load
    float wlo[4][2];
    float whi[4][2];
    bool  anyv = false;

#pragma unroll
    for (int j = 0; j < 4; ++j) {
        const float zf = -5.0f + (float)(iz0 + j) * 0.5f;

        const float px = fmaf(M[0][2], zf, px0);
        const float py = fmaf(M[1][2], zf, py0);
        const float pz = fmaf(M[2][2], zf, pz0);

        // x = (px/pz)*(W-1)/W ; y = (py/pz)*(H-1)/H  (algebraic fold of the
        // reference's u/v chain). rcp: pz=0 -> inf/NaN -> isfinite fallback.
        const float rz = __builtin_amdgcn_rcpf(pz);
        float x = px * rz * (87.0f / 88.0f);
        float y = py * rz * (31.0f / 32.0f);
        const bool fin = __builtin_isfinite(x) && __builtin_isfinite(y);
        x = fin ? x : -10.0f;
        y = fin ? y : -10.0f;

        const float x0 = floorf(x);
        const float y0 = floorf(y);
        const float x1 = x0 + 1.0f;
        const float y1 = y0 + 1.0f;
        const float wx1 = x - x0, wx0 = 1.0f - wx1;
        const float wy1 = y - y0, wy0 = 1.0f - wy1;

        const bool vx0 = (x0 >= 0.0f) && (x0 < (float)Ww);
        const bool vx1 = (x1 >= 0.0f) && (x1 < (float)Ww);
        const bool vy0 = (y0 >= 0.0f) && (y0 < (float)Hh);
        const bool vy1 = (y1 >= 0.0f) && (y1 < (float)Hh);
        const float w00 = (vx0 && vy0) ? wx0 * wy0 : 0.0f;
        const float w10 = (vx1 && vy0) ? wx1 * wy0 : 0.0f;
        const float w01 = (vx0 && vy1) ? wx0 * wy1 : 0.0f;
        const float w11 = (vx1 && vy1) ? wx1 * wy1 : 0.0f;

        const float xb  = fminf(fmaxf(x0, 0.0f), 86.0f);
        const float y0c = fminf(fmaxf(y0, 0.0f), 31.0f);
        const float y1c = fminf(fmaxf(y1, 0.0f), 31.0f);

        const int xbi = (int)xb;
        pix[j][0] = ((int)y0c * Ww + xbi) * 4;
        pix[j][1] = ((int)y1c * Ww + xbi) * 4;

        const float lo_is_x0 = (x0 == xb) ? 1.0f : 0.0f;
        const float lo_is_x1 = (x1 == xb) ? 1.0f : 0.0f;
        const float hi_is_x0 = (x0 == xb + 1.0f) ? 1.0f : 0.0f;
        const float hi_is_x1 = (x1 == xb + 1.0f) ? 1.0f : 0.0f;
        wlo[j][0] = lo_is_x0 * w00 + lo_is_x1 * w10;
        whi[j][0] = hi_is_x0 * w00 + hi_is_x1 * w10;
        wlo[j][1] = lo_is_x0 * w01 + lo_is_x1 * w11;
        whi[j][1] = hi_is_x0 * w01 + hi_is_x1 * w11;

        anyv |= (w00 + w10 + w01 + w11) > 0.0f;
    }

    float* ob = out + ((size_t)b * Cc + cq * CPB) * (size_t)NPT + n0;

    if (!anyv) {
        const float4 z4 = make_float4(0.0f, 0.0f, 0.0f, 0.0f);
#pragma unroll
        for (int q = 0; q < CPB; ++q)
            *reinterpret_cast<float4*>(ob + (size_t)q * NPT) = z4;
        return;
    }

    const unsigned short* fb = featH + ((size_t)b * NG + cq * NCGPB) * (size_t)(HWc * 4);

    // ---- software-pipelined gather loop: prefetch slice cg+1 while computing cg ----
    uint4 cur[8];
#pragma unroll
    for (int q = 0; q < 8; ++q)
        cur[q] = *reinterpret_cast<const uint4*>(fb + pix[q >> 1][q & 1]);

#pragma unroll
    for (int cg = 0; cg < NCGPB; ++cg) {
        uint4 nxt[8];
        if (cg + 1 < NCGPB) {
            const unsigned short* fgn = fb + (size_t)(cg + 1) * (HWc * 4);
#pragma unroll
            for (int q = 0; q < 8; ++q)
                nxt[q] = *reinterpret_cast<const uint4*>(fgn + pix[q >> 1][q & 1]);
        }

        float acc[4][4];   // [cc][j]
#pragma unroll
        for (int cc = 0; cc < 4; ++cc)
#pragma unroll
            for (int j = 0; j < 4; ++j) acc[cc][j] = 0.0f;

#pragma unroll
        for (int j = 0; j < 4; ++j) {
#pragma unroll
            for (int k = 0; k < 2; ++k) {
                const uint4 raw = cur[j * 2 + k];
                const float wl = wlo[j][k];
                const float wh = whi[j][k];
                const float2 lo01 = cvt2(raw.x);
                const float2 lo23 = cvt2(raw.y);
                const float2 hi01 = cvt2(raw.z);
                const float2 hi23 = cvt2(raw.w);
                acc[0][j] = fmaf(wl, lo01.x, fmaf(wh, hi01.x, acc[0][j]));
                acc[1][j] = fmaf(wl, lo01.y, fmaf(wh, hi01.y, acc[1][j]));
                acc[2][j] = fmaf(wl, lo23.x, fmaf(wh, hi23.x, acc[2][j]));
                acc[3][j] = fmaf(wl, lo23.y, fmaf(wh, hi23.y, acc[3][j]));
            }
        }

#pragma unroll
        for (int cc = 0; cc < 4; ++cc) {
            *reinterpret_cast<float4*>(ob + (size_t)(cg * 4 + cc) * NPT) =
                make_float4(acc[cc][0], acc[cc][1], acc[cc][2], acc[cc][3]);
        }

        if (cg + 1 < NCGPB) {
#pragma unroll
            for (int q = 0; q < 8; ++q) cur[q] = nxt[q];
        }
    }
}

extern "C" void kernel_launch(void* const* d_in, const int* in_sizes, int n_in,
                              void* d_out, int out_size, void* d_ws, size_t ws_size,
                              hipStream_t stream) {
    const float* feat   = (const float*)d_in[0];
    const float* intrin = (const float*)d_in[1];
    const float* extrin = (const float*)d_in[2];
    const float* bda    = (const float*)d_in[3];
    float* out = (float*)d_out;
    unsigned short* featH = (unsigned short*)d_ws;

    const int B = in_sizes[0] / (Cc * HWc);
    const int total = B * NG * HWc;

    fvt_tohalf<<<(total + 255) / 256, 256, 0, stream>>>(feat, featH, total);

    dim3 block(BLK);
    dim3 grid(NPT / 4 / BLK, B, CSPLIT);
    fvt_kernel<<<grid, block, 0, stream>>>(featH, intrin, extrin, bda, out);
}